// Round 1
// baseline (2468.387 us; speedup 1.0000x reference)
//
#include <hip/hip_runtime.h>
#include <math.h>

#define NN 16384
#define KK 16
#define TJ 256
#define TJP (TJ + 4)            // padded LDS row stride (floats); keeps b128 16B-aligned
#define ROWS_PER_BLOCK 16
#define ROWS_PER_WAVE 4
#define THREADS 256
#define NWAVES (THREADS / 64)

// ws float layout:
// [0]      total_s  = sum_{i,j} adj[i,j] * dot(C_i, C_j)
// [1]      m_sum    = sum(deg)
// [2..17]  dC[k]    = sum_i deg_i * C[i,k]
// [18..33] colsum[k]= sum_i C[i,k]

__global__ void zero_acc(float* ws) {
    int t = threadIdx.x;
    if (t < 64) ws[t] = 0.0f;
}

// lgkm-only barrier: drains LDS ops (required for staging correctness) but
// leaves global loads (vmcnt) in flight across the barrier -- the adj/C
// prefetches keep streaming while waves sync. Single asm blob so no memory
// op can be scheduled between the waitcnt and the s_barrier.
__device__ __forceinline__ void bar_lgkm() {
    asm volatile("s_waitcnt lgkmcnt(0)\n\ts_barrier" ::: "memory");
}

__global__ void __launch_bounds__(THREADS, 4)
k1_fused(const float* __restrict__ adj, const float* __restrict__ C,
         float* __restrict__ ws) {
    __shared__ float ct[2][KK * TJP];   // double-buffered transposed C tile
    __shared__ float red[NWAVES][34];

    const int tid  = threadIdx.x;
    const int lane = tid & 63;
    const int wave = __builtin_amdgcn_readfirstlane(tid >> 6);
    const int i0   = blockIdx.x * ROWS_PER_BLOCK + wave * ROWS_PER_WAVE;

    // C_i for this wave's 4 rows -> wave-uniform, force into SGPRs
    float ci[ROWS_PER_WAVE][KK];
    #pragma unroll
    for (int r = 0; r < ROWS_PER_WAVE; ++r) {
        #pragma unroll
        for (int k = 0; k < KK; ++k) {
            float v = C[(size_t)(i0 + r) * KK + k];
            ci[r][k] = __uint_as_float(
                __builtin_amdgcn_readfirstlane(__float_as_uint(v)));
        }
    }

    float s[ROWS_PER_WAVE]  = {0.f, 0.f, 0.f, 0.f};
    float dg[ROWS_PER_WAVE] = {0.f, 0.f, 0.f, 0.f};

    const float* arow[ROWS_PER_WAVE];
    #pragma unroll
    for (int r = 0; r < ROWS_PER_WAVE; ++r)
        arow[r] = adj + (size_t)(i0 + r) * NN + lane * 4;

    float4 a0[ROWS_PER_WAVE], a1[ROWS_PER_WAVE], cR[4];

#define PF_ADJ(A, JT) { \
    _Pragma("unroll") \
    for (int r = 0; r < ROWS_PER_WAVE; ++r) \
        A[r] = *(const float4*)(arow[r] + (JT)); }

#define PF_C(JT) { \
    _Pragma("unroll") \
    for (int it = 0; it < 4; ++it) \
        cR[it] = *(const float4*)(C + (size_t)(JT) * KK + tid * 4 + it * (THREADS * 4)); }

#define STAGE(BUF) { \
    _Pragma("unroll") \
    for (int it = 0; it < 4; ++it) { \
        const int idx = tid * 4 + it * (THREADS * 4); \
        const int j = idx >> 4, k0 = idx & 15; \
        (BUF)[(k0 + 0) * TJP + j] = cR[it].x; \
        (BUF)[(k0 + 1) * TJP + j] = cR[it].y; \
        (BUF)[(k0 + 2) * TJP + j] = cR[it].z; \
        (BUF)[(k0 + 3) * TJP + j] = cR[it].w; } }

#define COMPUTE(BUF, A) { \
    const int jo = lane * 4; \
    float d[ROWS_PER_WAVE][4] = {{0.f}}; \
    _Pragma("unroll") \
    for (int k = 0; k < KK; ++k) { \
        float4 c4 = *(const float4*)(&(BUF)[k * TJP + jo]); \
        _Pragma("unroll") \
        for (int r = 0; r < ROWS_PER_WAVE; ++r) { \
            d[r][0] += ci[r][k] * c4.x; \
            d[r][1] += ci[r][k] * c4.y; \
            d[r][2] += ci[r][k] * c4.z; \
            d[r][3] += ci[r][k] * c4.w; } } \
    _Pragma("unroll") \
    for (int r = 0; r < ROWS_PER_WAVE; ++r) { \
        s[r]  += A[r].x * d[r][0] + A[r].y * d[r][1] \
               + A[r].z * d[r][2] + A[r].w * d[r][3]; \
        dg[r] += A[r].x + A[r].y + A[r].z + A[r].w; } }

    // ---- prologue: adj tile 0 in flight, C tile 0 staged into ct[0]
    PF_ADJ(a0, 0);
    PF_C(0);
    STAGE(ct[0]);
    bar_lgkm();

    // ---- main loop, 2 tiles per iteration (register ping-pong, no copies)
    for (int jt = 0; jt < NN; jt += 2 * TJ) {
        // body A: compute tile jt from ct[0]/a0; prefetch tile jt+TJ
        PF_ADJ(a1, jt + TJ);
        PF_C(jt + TJ);
        COMPUTE(ct[0], a0);
        STAGE(ct[1]);
        bar_lgkm();

        // body B: compute tile jt+TJ from ct[1]/a1; prefetch tile jt+2*TJ
        const int jn = jt + 2 * TJ;
        if (jn < NN) {
            PF_ADJ(a0, jn);
            PF_C(jn);
        }
        COMPUTE(ct[1], a1);
        if (jn < NN) {
            STAGE(ct[0]);
        }
        bar_lgkm();
    }

#undef PF_ADJ
#undef PF_C
#undef STAGE
#undef COMPUTE

    // ---- wave-reduce s and deg across 64 lanes
    float tot = 0.f;
    #pragma unroll
    for (int r = 0; r < ROWS_PER_WAVE; ++r) {
        #pragma unroll
        for (int off = 32; off; off >>= 1) {
            s[r]  += __shfl_xor(s[r],  off, 64);
            dg[r] += __shfl_xor(dg[r], off, 64);
        }
        tot += s[r];
    }

    // ---- fused k2: per-wave dC[k], colsum[k], m contributions (wave-uniform)
    if (lane == 0) {
        #pragma unroll
        for (int k = 0; k < KK; ++k) {
            float a = 0.f, b = 0.f;
            #pragma unroll
            for (int r = 0; r < ROWS_PER_WAVE; ++r) {
                a += dg[r] * ci[r][k];
                b += ci[r][k];
            }
            red[wave][k]      = a;
            red[wave][16 + k] = b;
        }
        red[wave][32] = dg[0] + dg[1] + dg[2] + dg[3];
        red[wave][33] = tot;
    }
    __syncthreads();
    if (tid < 34) {
        float acc = red[0][tid] + red[1][tid] + red[2][tid] + red[3][tid];
        if (tid < 32)       atomicAdd(&ws[2 + tid], acc);   // dC + colsum (contiguous)
        else if (tid == 32) atomicAdd(&ws[1], acc);         // m_sum
        else                atomicAdd(&ws[0], acc);         // total_s
    }
}

__global__ void k3_final(const float* __restrict__ ws,
                         const float* __restrict__ beta,
                         float* __restrict__ out) {
    if (threadIdx.x == 0 && blockIdx.x == 0) {
        double total_s = (double)ws[0];
        double m       = (double)ws[1] * 0.5;
        double dd = 0.0;
        for (int k = 0; k < KK; ++k)
            dd += (double)ws[2 + k] * (double)ws[2 + k];
        double mod_term = total_s - dd / (2.0 * m);
        double mod_loss = -mod_term / (2.0 * m);
        double col = 0.0;
        for (int k = 0; k < KK; ++k)
            col += fabs((double)ws[18 + k] - 1.0);
        double res = mod_loss + (double)beta[0] * (4.0 / 16384.0) * col;
        out[0] = (float)res;
    }
}

extern "C" void kernel_launch(void* const* d_in, const int* in_sizes, int n_in,
                              void* d_out, int out_size, void* d_ws, size_t ws_size,
                              hipStream_t stream) {
    const float* C    = (const float*)d_in[0];
    // d_in[1] = X, unused by the reference loss
    const float* adj  = (const float*)d_in[2];
    const float* beta = (const float*)d_in[3];
    float* ws  = (float*)d_ws;
    float* out = (float*)d_out;

    zero_acc<<<1, 64, 0, stream>>>(ws);
    k1_fused<<<NN / ROWS_PER_BLOCK, THREADS, 0, stream>>>(adj, C, ws);
    k3_final<<<1, 64, 0, stream>>>(ws, beta, out);
}